// Round 22
// baseline (127.853 us; speedup 1.0000x reference)
//
#include <hip/hip_runtime.h>
#include <math.h>

#define NTOK 65536
#define DIMD 128
#define KCB  2048
#define NSLAB 512   // one histogram slab per pass1 block

typedef unsigned short u16;
typedef __attribute__((ext_vector_type(8))) unsigned short u16x8;
typedef __attribute__((ext_vector_type(8))) __bf16 bf16x8;
typedef __attribute__((ext_vector_type(4))) float f32x4;

union U8 { u16x8 u; bf16x8 b; };

__device__ __forceinline__ u16 f2bf(float f) {
  union { float f; unsigned u; } c; c.f = f;
  unsigned r = c.u + 0x7FFFu + ((c.u >> 16) & 1u);
  return (u16)(r >> 16);
}
__device__ __forceinline__ float bf2f(u16 h) {
  union { unsigned u; float f; } c; c.u = ((unsigned)h) << 16;
  return c.f;
}

// linear tile staging: thread tid covers bytes [tid*16 + i*4096]; dest mirrors source
__device__ __forceinline__ void stage8(const char* srcLane, char* ldsWaveBase) {
  #pragma unroll
  for (int i = 0; i < 8; ++i)
    __builtin_amdgcn_global_load_lds((const __attribute__((address_space(1))) void*)(srcLane + i * 4096),
                                     (__attribute__((address_space(3))) void*)(ldsWaveBase + i * 4096), 16, 0, 0);
}

// ---------------- small kernels ----------------

// pack codebook to bf16 H+L in MFMA-fragment order, 64-code tiles (R8 layout); gid 0 zeroes acc
__global__ __launch_bounds__(256) void k_packcb(const float* __restrict__ cb, u16* __restrict__ cbp,
                                                float* __restrict__ acc4) {
  const int gid = blockIdx.x * 256 + threadIdx.x;
  if (gid == 0) { acc4[0] = 0.0f; acc4[1] = 0.0f; acc4[2] = 0.0f; acc4[3] = 0.0f; }
  if (gid >= 32768) return;
  const int lane = gid & 63;
  const int f = (gid >> 6) & 15;
  const int T = gid >> 10;
  const int ks = f >> 2, nf = f & 3;
  const int hi = lane >> 4, l15 = lane & 15;
  const int c = T * 64 + nf * 16 + l15;
  const int d0 = ks * 32 + hi * 8;
  const float4 v0 = *(const float4*)(cb + (size_t)c * DIMD + d0);
  const float4 v1 = *(const float4*)(cb + (size_t)c * DIMD + d0 + 4);
  const float e[8] = {v0.x, v0.y, v0.z, v0.w, v1.x, v1.y, v1.z, v1.w};
  union { u16 s[8]; u16x8 u; } oh, ol;
  #pragma unroll
  for (int i = 0; i < 8; ++i) {
    const u16 h = f2bf(e[i]);
    oh.s[i] = h;
    ol.s[i] = f2bf(e[i] - bf2f(h));
  }
  u16* tile = cbp + (size_t)T * 16384;
  *(u16x8*)(tile + (f * 64 + lane) * 8) = oh.u;
  *(u16x8*)(tile + 8192 + (f * 64 + lane) * 8) = ol.u;
}

// ---------------- MFMA pass 1: split precision, fused x-norm + gather + histogram + stats ----------------
// single-barrier pipeline; after the K-loop the 64KB LDS is reused as the per-block
// avg_probs/code_count histogram (written out as one slab per block, no global atomics).

__global__ __launch_bounds__(256, 2) void k_pass1(const float* __restrict__ x, const float* __restrict__ mask,
                                                  const float* __restrict__ cb, const u16* __restrict__ cbp,
                                                  float* __restrict__ outQ, float* __restrict__ outEnc,
                                                  float* __restrict__ apPart, float* __restrict__ cnPart,
                                                  float* __restrict__ acc4) {
  __shared__ __align__(16) char Bsmem[65536];  // 2 x (16KB H + 16KB L); reused as histograms at tail
  const int tid = threadIdx.x;
  const int lane = tid & 63, w = tid >> 6;
  const int l15 = lane & 15, hi = lane >> 4;
  const int row0 = blockIdx.x * 128;
  const char* src = (const char*)cbp;

  // fused prep: load x f32, row-norm via 2-step shuffle (4 lanes/row), split to bf16 H+L in regs
  U8 Ah[2][4], Al[2][4];
  #pragma unroll
  for (int mf = 0; mf < 2; ++mf) {
    const int row = row0 + w * 32 + mf * 16 + l15;
    const float add = (1.0f - mask[row]) * 1e-6f;
    const float* xr = x + (size_t)row * DIMD + hi * 8;
    float xf[4][8];
    float ss = 0.f;
    #pragma unroll
    for (int ks = 0; ks < 4; ++ks) {
      const float4 a = *(const float4*)(xr + ks * 32);
      const float4 bq = *(const float4*)(xr + ks * 32 + 4);
      xf[ks][0] = a.x + add;  xf[ks][1] = a.y + add;  xf[ks][2] = a.z + add;  xf[ks][3] = a.w + add;
      xf[ks][4] = bq.x + add; xf[ks][5] = bq.y + add; xf[ks][6] = bq.z + add; xf[ks][7] = bq.w + add;
      #pragma unroll
      for (int e = 0; e < 8; ++e) ss = fmaf(xf[ks][e], xf[ks][e], ss);
    }
    ss += __shfl_xor(ss, 16, 64);
    ss += __shfl_xor(ss, 32, 64);
    const float sc = 1.0f / fmaxf(sqrtf(ss), 1e-6f);
    #pragma unroll
    for (int ks = 0; ks < 4; ++ks) {
      union { u16 s[8]; u16x8 u; } th, tl;
      #pragma unroll
      for (int e = 0; e < 8; ++e) {
        const float xn = xf[ks][e] * sc;
        const u16 h = f2bf(xn);
        th.s[e] = h;
        tl.s[e] = f2bf(xn - bf2f(h));
      }
      Ah[mf][ks].u = th.u;
      Al[mf][ks].u = tl.u;
    }
  }

  float v1[8];
  int k1[8];
  #pragma unroll
  for (int r = 0; r < 8; ++r) { v1[r] = -1e30f; k1[r] = 0; }

  stage8(src + 0 * 32768 + tid * 16, Bsmem + 0 * 32768 + w * 1024);

  for (int t = 0; t < 32; ++t) {
    const int b = t & 1;
    asm volatile("s_waitcnt vmcnt(0)" ::: "memory");
    __builtin_amdgcn_sched_barrier(0);
    __builtin_amdgcn_s_barrier();
    __builtin_amdgcn_sched_barrier(0);
    if (t < 31)
      stage8(src + (size_t)(t + 1) * 32768 + tid * 16, Bsmem + (b ^ 1) * 32768 + w * 1024);

    const char* base = Bsmem + b * 32768 + lane * 16;
    f32x4 acc[2][4];
    #pragma unroll
    for (int m = 0; m < 2; ++m)
      #pragma unroll
      for (int nf = 0; nf < 4; ++nf) acc[m][nf] = (f32x4){0.f, 0.f, 0.f, 0.f};

    __builtin_amdgcn_s_setprio(1);
    #pragma unroll
    for (int ks = 0; ks < 4; ++ks) {
      #pragma unroll
      for (int nf = 0; nf < 4; ++nf) {
        U8 bh, bl;
        bh.u = *(const u16x8*)(base + ((ks * 4 + nf) << 10));
        bl.u = *(const u16x8*)(base + 16384 + ((ks * 4 + nf) << 10));
        acc[0][nf] = __builtin_amdgcn_mfma_f32_16x16x32_bf16(Ah[0][ks].b, bh.b, acc[0][nf], 0, 0, 0);
        acc[1][nf] = __builtin_amdgcn_mfma_f32_16x16x32_bf16(Ah[1][ks].b, bh.b, acc[1][nf], 0, 0, 0);
        acc[0][nf] = __builtin_amdgcn_mfma_f32_16x16x32_bf16(Al[0][ks].b, bh.b, acc[0][nf], 0, 0, 0);
        acc[1][nf] = __builtin_amdgcn_mfma_f32_16x16x32_bf16(Al[1][ks].b, bh.b, acc[1][nf], 0, 0, 0);
        acc[0][nf] = __builtin_amdgcn_mfma_f32_16x16x32_bf16(Ah[0][ks].b, bl.b, acc[0][nf], 0, 0, 0);
        acc[1][nf] = __builtin_amdgcn_mfma_f32_16x16x32_bf16(Ah[1][ks].b, bl.b, acc[1][nf], 0, 0, 0);
      }
    }
    __builtin_amdgcn_s_setprio(0);

    // epilogue: PER-LANE top-1 only (branchless; registers only; overlaps in-flight prefetch)
    const int colbase = t * 64 + l15;
    #pragma unroll
    for (int m = 0; m < 2; ++m)
      #pragma unroll
      for (int rg = 0; rg < 4; ++rg) {
        const int r = m * 4 + rg;
        float vv = v1[r];
        int kk = k1[r];
        #pragma unroll
        for (int nf = 0; nf < 4; ++nf) {
          const float xv = acc[m][nf][rg];
          const bool gt = xv > vv;              // strict > keeps first (lowest) index
          kk = gt ? (colbase + nf * 16) : kk;
          vv = gt ? xv : vv;
        }
        v1[r] = vv; k1[r] = kk;
      }
  }

  // ---- tail: reuse LDS as per-block histograms; merge + gather + stats ----
  __syncthreads();  // all waves done reading Bsmem (MFMA consumed all ds_reads)
  float* apLds = (float*)Bsmem;            // [KCB]
  float* cnLds = (float*)Bsmem + KCB;      // [KCB]
  float* smr = (float*)Bsmem + 2 * KCB;    // [12]
  for (int i = tid; i < 2 * KCB; i += 256) ((float*)Bsmem)[i] = 0.0f;
  __syncthreads();

  float msum = 0.f, slat = 0.f, sent = 0.f;
  #pragma unroll
  for (int m = 0; m < 2; ++m)
    #pragma unroll
    for (int rg = 0; rg < 4; ++rg) {
      const int r = m * 4 + rg;
      float a1 = v1[r];
      int ak = k1[r];
      #pragma unroll
      for (int off = 1; off <= 8; off <<= 1) {
        const float o1 = __shfl_xor(a1, off, 64);
        const int okk = __shfl_xor(ak, off, 64);
        const bool take = (o1 > a1) || (o1 == a1 && okk < ak);
        a1 = take ? o1 : a1;
        ak = take ? okk : ak;
      }
      const int row = row0 + w * 32 + m * 16 + hi * 4 + rg;
      const float mk = mask[row];
      // per-lane candidate weight vs merged max (same formula as the old scatter kernel)
      float q = 0.f, qd = 0.f;
      if (v1[r] > a1 - 0.055f) {
        const float d = 200.f * (v1[r] - a1);
        q = __expf(d);
        qd = q * d;
      }
      float Z = q, S = qd;
      #pragma unroll
      for (int off = 1; off <= 8; off <<= 1) {
        Z += __shfl_xor(Z, off, 64);
        S += __shfl_xor(S, off, 64);
      }
      if (q > 0.f) atomicAdd(&apLds[k1[r]], mk * q / Z);
      // fused gather: 16 lanes write the selected codebook row (cb is L2-resident)
      const float4 g0 = *(const float4*)(cb + (size_t)ak * DIMD + l15 * 8);
      const float4 g1 = *(const float4*)(cb + (size_t)ak * DIMD + l15 * 8 + 4);
      *(float4*)(outQ + (size_t)row * DIMD + l15 * 8) = g0;
      *(float4*)(outQ + (size_t)row * DIMD + l15 * 8 + 4) = g1;
      if (l15 == 0) {
        atomicAdd(&cnLds[ak], mk);
        outEnc[row] = (float)ak;
        msum += mk;
        slat = fmaf(mk, 2.0f - 2.0f * a1, slat);
        sent = fmaf(mk, __logf(Z) - S / Z, sent);
      }
    }
  // block-reduce the three scalars (only l15==0 lanes hold nonzero)
  #pragma unroll
  for (int off = 32; off; off >>= 1) {
    msum += __shfl_xor(msum, off, 64);
    slat += __shfl_xor(slat, off, 64);
    sent += __shfl_xor(sent, off, 64);
  }
  if (lane == 0) { smr[w * 3] = msum; smr[w * 3 + 1] = slat; smr[w * 3 + 2] = sent; }
  __syncthreads();
  if (tid == 0) {
    float t0 = 0.f, t1 = 0.f, t2 = 0.f;
    #pragma unroll
    for (int v = 0; v < 4; ++v) { t0 += smr[v * 3]; t1 += smr[v * 3 + 1]; t2 += smr[v * 3 + 2]; }
    atomicAdd(&acc4[0], t0);
    atomicAdd(&acc4[1], t1);
    atomicAdd(&acc4[2], t2);
  }
  // write per-block histogram slabs (plain coalesced stores)
  float* apDst = apPart + (size_t)blockIdx.x * KCB;
  float* cnDst = cnPart + (size_t)blockIdx.x * KCB;
  for (int i = tid; i < KCB; i += 256) {
    apDst[i] = apLds[i];
    cnDst[i] = cnLds[i];
  }
}

// reduce partial slabs -> avgp-entropy partials + outCnt. 64 blocks x 256 threads, coalesced.
// block b owns k in [b*32, b*32+32); thread (sg=tid>>5, kloc=tid&31) sums slabs sg*64..+64.
__global__ __launch_bounds__(256) void k_reduce(const float* __restrict__ apPart, const float* __restrict__ cnPart,
                                                const float* __restrict__ acc4In, float* __restrict__ outCnt,
                                                float* __restrict__ acc4) {
  __shared__ float sa8[8][32];
  __shared__ float sc8[8][32];
  const int tid = threadIdx.x;
  const int kloc = tid & 31, sg = tid >> 5;
  const int k = blockIdx.x * 32 + kloc;
  float sa = 0.f, sc = 0.f;
  #pragma unroll
  for (int i = 0; i < 64; ++i) {
    const int s = sg * 64 + i;
    sa += apPart[(size_t)s * KCB + k];
    sc += cnPart[(size_t)s * KCB + k];
  }
  sa8[sg][kloc] = sa;
  sc8[sg][kloc] = sc;
  __syncthreads();
  if (tid < 32) {
    float ta = 0.f, tc = 0.f;
    #pragma unroll
    for (int g = 0; g < 8; ++g) { ta += sa8[g][tid]; tc += sc8[g][tid]; }
    outCnt[blockIdx.x * 32 + tid] = tc;
    // fused avg-probs entropy partial: a*log(a+1e-5), a = avgp_k / msum (msum ready: pass1 precedes)
    const float a = ta / acc4In[0];
    float ae = a * __logf(a + 1e-5f);
    #pragma unroll
    for (int off = 1; off <= 16; off <<= 1) ae += __shfl_xor(ae, off, 64);
    if (tid == 0) atomicAdd(&acc4[3], ae);
  }
}

__global__ __launch_bounds__(64) void k_final(const float* __restrict__ acc4, float* __restrict__ out3) {
  if (threadIdx.x == 0) {
    const float msum = acc4[0];
    const float lat = acc4[1] / (msum + 1e-6f);
    out3[0] = lat;
    out3[1] = lat;
    out3[2] = acc4[2] / msum + acc4[3];  // sample_entropy - avg_entropy
  }
}

// ---------------- launcher ----------------

extern "C" void kernel_launch(void* const* d_in, const int* in_sizes, int n_in,
                              void* d_out, int out_size, void* d_ws, size_t ws_size,
                              hipStream_t stream) {
  const float* x = (const float*)d_in[0];
  const float* mask = (const float*)d_in[1];
  const float* cb = (const float*)d_in[2];

  float* out = (float*)d_out;
  float* outQ = out;
  float* out3 = out + (size_t)NTOK * DIMD;
  float* outCnt = out3 + 3;
  float* outEnc = outCnt + KCB;

  float* ws = (float*)d_ws;
  float* acc4 = ws;                                       // 4
  u16* cbp = (u16*)(acc4 + 8);                            // K*D*2 u16 (1 MB)
  float* apPart = (float*)(cbp + (size_t)KCB * DIMD * 2); // NSLAB*K (4 MB)
  float* cnPart = apPart + (size_t)NSLAB * KCB;           // NSLAB*K (4 MB)

  k_packcb<<<32768 / 256, 256, 0, stream>>>(cb, cbp, acc4);
  k_pass1<<<NTOK / 128, 256, 0, stream>>>(x, mask, cb, cbp, outQ, outEnc, apPart, cnPart, acc4);
  k_reduce<<<64, 256, 0, stream>>>(apPart, cnPart, acc4, outCnt, acc4);
  k_final<<<1, 64, 0, stream>>>(acc4, out3);
}

// Round 23
// 125.485 us; speedup vs baseline: 1.0189x; 1.0189x over previous
//
#include <hip/hip_runtime.h>
#include <math.h>

#define NTOK 65536
#define DIMD 128
#define KCB  2048
#define NSLAB 512   // one histogram slab per pass1 block

typedef unsigned short u16;
typedef __attribute__((ext_vector_type(8))) unsigned short u16x8;
typedef __attribute__((ext_vector_type(8))) __bf16 bf16x8;
typedef __attribute__((ext_vector_type(4))) float f32x4;

union U8 { u16x8 u; bf16x8 b; };

__device__ __forceinline__ u16 f2bf(float f) {
  union { float f; unsigned u; } c; c.f = f;
  unsigned r = c.u + 0x7FFFu + ((c.u >> 16) & 1u);
  return (u16)(r >> 16);
}
__device__ __forceinline__ float bf2f(u16 h) {
  union { unsigned u; float f; } c; c.u = ((unsigned)h) << 16;
  return c.f;
}

// linear tile staging: thread tid covers bytes [tid*16 + i*4096]; dest mirrors source
__device__ __forceinline__ void stage8(const char* srcLane, char* ldsWaveBase) {
  #pragma unroll
  for (int i = 0; i < 8; ++i)
    __builtin_amdgcn_global_load_lds((const __attribute__((address_space(1))) void*)(srcLane + i * 4096),
                                     (__attribute__((address_space(3))) void*)(ldsWaveBase + i * 4096), 16, 0, 0);
}

// ---------------- small kernels ----------------

// pack codebook to bf16 H+L in MFMA-fragment order, 64-code tiles (R8 layout); gid 0 zeroes acc
__global__ __launch_bounds__(256) void k_packcb(const float* __restrict__ cb, u16* __restrict__ cbp,
                                                float* __restrict__ acc4) {
  const int gid = blockIdx.x * 256 + threadIdx.x;
  if (gid == 0) { acc4[0] = 0.0f; acc4[1] = 0.0f; acc4[2] = 0.0f; acc4[3] = 0.0f; }
  if (gid >= 32768) return;
  const int lane = gid & 63;
  const int f = (gid >> 6) & 15;
  const int T = gid >> 10;
  const int ks = f >> 2, nf = f & 3;
  const int hi = lane >> 4, l15 = lane & 15;
  const int c = T * 64 + nf * 16 + l15;
  const int d0 = ks * 32 + hi * 8;
  const float4 v0 = *(const float4*)(cb + (size_t)c * DIMD + d0);
  const float4 v1 = *(const float4*)(cb + (size_t)c * DIMD + d0 + 4);
  const float e[8] = {v0.x, v0.y, v0.z, v0.w, v1.x, v1.y, v1.z, v1.w};
  union { u16 s[8]; u16x8 u; } oh, ol;
  #pragma unroll
  for (int i = 0; i < 8; ++i) {
    const u16 h = f2bf(e[i]);
    oh.s[i] = h;
    ol.s[i] = f2bf(e[i] - bf2f(h));
  }
  u16* tile = cbp + (size_t)T * 16384;
  *(u16x8*)(tile + (f * 64 + lane) * 8) = oh.u;
  *(u16x8*)(tile + 8192 + (f * 64 + lane) * 8) = ol.u;
}

// ---------------- MFMA pass 1: split precision, fused x-norm + gather + histogram + stats ----------------
// single-barrier pipeline; B-fragments pre-loaded per ks so same-accumulator MFMA
// dependency distance is 8 (covers MFMA latency); accumulation order per acc unchanged.

__global__ __launch_bounds__(256, 2) void k_pass1(const float* __restrict__ x, const float* __restrict__ mask,
                                                  const float* __restrict__ cb, const u16* __restrict__ cbp,
                                                  float* __restrict__ outQ, float* __restrict__ outEnc,
                                                  float* __restrict__ apPart, float* __restrict__ cnPart,
                                                  float* __restrict__ acc4) {
  __shared__ __align__(16) char Bsmem[65536];  // 2 x (16KB H + 16KB L); reused as histograms at tail
  const int tid = threadIdx.x;
  const int lane = tid & 63, w = tid >> 6;
  const int l15 = lane & 15, hi = lane >> 4;
  const int row0 = blockIdx.x * 128;
  const char* src = (const char*)cbp;

  // fused prep: load x f32, row-norm via 2-step shuffle (4 lanes/row), split to bf16 H+L in regs
  U8 Ah[2][4], Al[2][4];
  #pragma unroll
  for (int mf = 0; mf < 2; ++mf) {
    const int row = row0 + w * 32 + mf * 16 + l15;
    const float add = (1.0f - mask[row]) * 1e-6f;
    const float* xr = x + (size_t)row * DIMD + hi * 8;
    float xf[4][8];
    float ss = 0.f;
    #pragma unroll
    for (int ks = 0; ks < 4; ++ks) {
      const float4 a = *(const float4*)(xr + ks * 32);
      const float4 bq = *(const float4*)(xr + ks * 32 + 4);
      xf[ks][0] = a.x + add;  xf[ks][1] = a.y + add;  xf[ks][2] = a.z + add;  xf[ks][3] = a.w + add;
      xf[ks][4] = bq.x + add; xf[ks][5] = bq.y + add; xf[ks][6] = bq.z + add; xf[ks][7] = bq.w + add;
      #pragma unroll
      for (int e = 0; e < 8; ++e) ss = fmaf(xf[ks][e], xf[ks][e], ss);
    }
    ss += __shfl_xor(ss, 16, 64);
    ss += __shfl_xor(ss, 32, 64);
    const float sc = 1.0f / fmaxf(sqrtf(ss), 1e-6f);
    #pragma unroll
    for (int ks = 0; ks < 4; ++ks) {
      union { u16 s[8]; u16x8 u; } th, tl;
      #pragma unroll
      for (int e = 0; e < 8; ++e) {
        const float xn = xf[ks][e] * sc;
        const u16 h = f2bf(xn);
        th.s[e] = h;
        tl.s[e] = f2bf(xn - bf2f(h));
      }
      Ah[mf][ks].u = th.u;
      Al[mf][ks].u = tl.u;
    }
  }

  float v1[8];
  int k1[8];
  #pragma unroll
  for (int r = 0; r < 8; ++r) { v1[r] = -1e30f; k1[r] = 0; }

  stage8(src + 0 * 32768 + tid * 16, Bsmem + 0 * 32768 + w * 1024);

  for (int t = 0; t < 32; ++t) {
    const int b = t & 1;
    asm volatile("s_waitcnt vmcnt(0)" ::: "memory");
    __builtin_amdgcn_sched_barrier(0);
    __builtin_amdgcn_s_barrier();
    __builtin_amdgcn_sched_barrier(0);
    if (t < 31)
      stage8(src + (size_t)(t + 1) * 32768 + tid * 16, Bsmem + (b ^ 1) * 32768 + w * 1024);

    const char* base = Bsmem + b * 32768 + lane * 16;
    f32x4 acc[2][4];
    #pragma unroll
    for (int m = 0; m < 2; ++m)
      #pragma unroll
      for (int nf = 0; nf < 4; ++nf) acc[m][nf] = (f32x4){0.f, 0.f, 0.f, 0.f};

    __builtin_amdgcn_s_setprio(1);
    #pragma unroll
    for (int ks = 0; ks < 4; ++ks) {
      // load all 8 B-fragments for this ks first, then pure-register MFMA burst
      U8 bh[4], bl[4];
      #pragma unroll
      for (int nf = 0; nf < 4; ++nf) {
        bh[nf].u = *(const u16x8*)(base + ((ks * 4 + nf) << 10));
        bl[nf].u = *(const u16x8*)(base + 16384 + ((ks * 4 + nf) << 10));
      }
      // same per-accumulator order as before (Ah*bh, Al*bh, Ah*bl) => bit-identical results,
      // but same-acc dependency distance is now 8 instructions
      #pragma unroll
      for (int nf = 0; nf < 4; ++nf) {
        acc[0][nf] = __builtin_amdgcn_mfma_f32_16x16x32_bf16(Ah[0][ks].b, bh[nf].b, acc[0][nf], 0, 0, 0);
        acc[1][nf] = __builtin_amdgcn_mfma_f32_16x16x32_bf16(Ah[1][ks].b, bh[nf].b, acc[1][nf], 0, 0, 0);
      }
      #pragma unroll
      for (int nf = 0; nf < 4; ++nf) {
        acc[0][nf] = __builtin_amdgcn_mfma_f32_16x16x32_bf16(Al[0][ks].b, bh[nf].b, acc[0][nf], 0, 0, 0);
        acc[1][nf] = __builtin_amdgcn_mfma_f32_16x16x32_bf16(Al[1][ks].b, bh[nf].b, acc[1][nf], 0, 0, 0);
      }
      #pragma unroll
      for (int nf = 0; nf < 4; ++nf) {
        acc[0][nf] = __builtin_amdgcn_mfma_f32_16x16x32_bf16(Ah[0][ks].b, bl[nf].b, acc[0][nf], 0, 0, 0);
        acc[1][nf] = __builtin_amdgcn_mfma_f32_16x16x32_bf16(Ah[1][ks].b, bl[nf].b, acc[1][nf], 0, 0, 0);
      }
    }
    __builtin_amdgcn_s_setprio(0);

    // epilogue: PER-LANE top-1 only (branchless; registers only; overlaps in-flight prefetch)
    const int colbase = t * 64 + l15;
    #pragma unroll
    for (int m = 0; m < 2; ++m)
      #pragma unroll
      for (int rg = 0; rg < 4; ++rg) {
        const int r = m * 4 + rg;
        float vv = v1[r];
        int kk = k1[r];
        #pragma unroll
        for (int nf = 0; nf < 4; ++nf) {
          const float xv = acc[m][nf][rg];
          const bool gt = xv > vv;              // strict > keeps first (lowest) index
          kk = gt ? (colbase + nf * 16) : kk;
          vv = gt ? xv : vv;
        }
        v1[r] = vv; k1[r] = kk;
      }
  }

  // ---- tail: reuse LDS as per-block histograms; merge + gather + stats ----
  __syncthreads();  // all waves done reading Bsmem (MFMA consumed all ds_reads)
  float* apLds = (float*)Bsmem;            // [KCB]
  float* cnLds = (float*)Bsmem + KCB;      // [KCB]
  float* smr = (float*)Bsmem + 2 * KCB;    // [12]
  for (int i = tid; i < 2 * KCB; i += 256) ((float*)Bsmem)[i] = 0.0f;
  __syncthreads();

  float msum = 0.f, slat = 0.f, sent = 0.f;
  #pragma unroll
  for (int m = 0; m < 2; ++m)
    #pragma unroll
    for (int rg = 0; rg < 4; ++rg) {
      const int r = m * 4 + rg;
      float a1 = v1[r];
      int ak = k1[r];
      #pragma unroll
      for (int off = 1; off <= 8; off <<= 1) {
        const float o1 = __shfl_xor(a1, off, 64);
        const int okk = __shfl_xor(ak, off, 64);
        const bool take = (o1 > a1) || (o1 == a1 && okk < ak);
        a1 = take ? o1 : a1;
        ak = take ? okk : ak;
      }
      const int row = row0 + w * 32 + m * 16 + hi * 4 + rg;
      const float mk = mask[row];
      // per-lane candidate weight vs merged max (same formula as the old scatter kernel)
      float q = 0.f, qd = 0.f;
      if (v1[r] > a1 - 0.055f) {
        const float d = 200.f * (v1[r] - a1);
        q = __expf(d);
        qd = q * d;
      }
      float Z = q, S = qd;
      #pragma unroll
      for (int off = 1; off <= 8; off <<= 1) {
        Z += __shfl_xor(Z, off, 64);
        S += __shfl_xor(S, off, 64);
      }
      if (q > 0.f) atomicAdd(&apLds[k1[r]], mk * q / Z);
      // fused gather: 16 lanes write the selected codebook row (cb is L2-resident)
      const float4 g0 = *(const float4*)(cb + (size_t)ak * DIMD + l15 * 8);
      const float4 g1 = *(const float4*)(cb + (size_t)ak * DIMD + l15 * 8 + 4);
      *(float4*)(outQ + (size_t)row * DIMD + l15 * 8) = g0;
      *(float4*)(outQ + (size_t)row * DIMD + l15 * 8 + 4) = g1;
      if (l15 == 0) {
        atomicAdd(&cnLds[ak], mk);
        outEnc[row] = (float)ak;
        msum += mk;
        slat = fmaf(mk, 2.0f - 2.0f * a1, slat);
        sent = fmaf(mk, __logf(Z) - S / Z, sent);
      }
    }
  // block-reduce the three scalars (only l15==0 lanes hold nonzero)
  #pragma unroll
  for (int off = 32; off; off >>= 1) {
    msum += __shfl_xor(msum, off, 64);
    slat += __shfl_xor(slat, off, 64);
    sent += __shfl_xor(sent, off, 64);
  }
  if (lane == 0) { smr[w * 3] = msum; smr[w * 3 + 1] = slat; smr[w * 3 + 2] = sent; }
  __syncthreads();
  if (tid == 0) {
    float t0 = 0.f, t1 = 0.f, t2 = 0.f;
    #pragma unroll
    for (int v = 0; v < 4; ++v) { t0 += smr[v * 3]; t1 += smr[v * 3 + 1]; t2 += smr[v * 3 + 2]; }
    atomicAdd(&acc4[0], t0);
    atomicAdd(&acc4[1], t1);
    atomicAdd(&acc4[2], t2);
  }
  // write per-block histogram slabs (plain coalesced stores)
  float* apDst = apPart + (size_t)blockIdx.x * KCB;
  float* cnDst = cnPart + (size_t)blockIdx.x * KCB;
  for (int i = tid; i < KCB; i += 256) {
    apDst[i] = apLds[i];
    cnDst[i] = cnLds[i];
  }
}

// reduce partial slabs -> avgp-entropy partials + outCnt. 64 blocks x 256 threads, coalesced.
// block b owns k in [b*32, b*32+32); thread (sg=tid>>5, kloc=tid&31) sums slabs sg*64..+64.
__global__ __launch_bounds__(256) void k_reduce(const float* __restrict__ apPart, const float* __restrict__ cnPart,
                                                const float* __restrict__ acc4In, float* __restrict__ outCnt,
                                                float* __restrict__ acc4) {
  __shared__ float sa8[8][32];
  __shared__ float sc8[8][32];
  const int tid = threadIdx.x;
  const int kloc = tid & 31, sg = tid >> 5;
  const int k = blockIdx.x * 32 + kloc;
  float sa = 0.f, sc = 0.f;
  #pragma unroll
  for (int i = 0; i < 64; ++i) {
    const int s = sg * 64 + i;
    sa += apPart[(size_t)s * KCB + k];
    sc += cnPart[(size_t)s * KCB + k];
  }
  sa8[sg][kloc] = sa;
  sc8[sg][kloc] = sc;
  __syncthreads();
  if (tid < 32) {
    float ta = 0.f, tc = 0.f;
    #pragma unroll
    for (int g = 0; g < 8; ++g) { ta += sa8[g][tid]; tc += sc8[g][tid]; }
    outCnt[blockIdx.x * 32 + tid] = tc;
    // fused avg-probs entropy partial: a*log(a+1e-5), a = avgp_k / msum (msum ready: pass1 precedes)
    const float a = ta / acc4In[0];
    float ae = a * __logf(a + 1e-5f);
    #pragma unroll
    for (int off = 1; off <= 16; off <<= 1) ae += __shfl_xor(ae, off, 64);
    if (tid == 0) atomicAdd(&acc4[3], ae);
  }
}

__global__ __launch_bounds__(64) void k_final(const float* __restrict__ acc4, float* __restrict__ out3) {
  if (threadIdx.x == 0) {
    const float msum = acc4[0];
    const float lat = acc4[1] / (msum + 1e-6f);
    out3[0] = lat;
    out3[1] = lat;
    out3[2] = acc4[2] / msum + acc4[3];  // sample_entropy - avg_entropy
  }
}

// ---------------- launcher ----------------

extern "C" void kernel_launch(void* const* d_in, const int* in_sizes, int n_in,
                              void* d_out, int out_size, void* d_ws, size_t ws_size,
                              hipStream_t stream) {
  const float* x = (const float*)d_in[0];
  const float* mask = (const float*)d_in[1];
  const float* cb = (const float*)d_in[2];

  float* out = (float*)d_out;
  float* outQ = out;
  float* out3 = out + (size_t)NTOK * DIMD;
  float* outCnt = out3 + 3;
  float* outEnc = outCnt + KCB;

  float* ws = (float*)d_ws;
  float* acc4 = ws;                                       // 4
  u16* cbp = (u16*)(acc4 + 8);                            // K*D*2 u16 (1 MB)
  float* apPart = (float*)(cbp + (size_t)KCB * DIMD * 2); // NSLAB*K (4 MB)
  float* cnPart = apPart + (size_t)NSLAB * KCB;           // NSLAB*K (4 MB)

  k_packcb<<<32768 / 256, 256, 0, stream>>>(cb, cbp, acc4);
  k_pass1<<<NTOK / 128, 256, 0, stream>>>(x, mask, cb, cbp, outQ, outEnc, apPart, cnPart, acc4);
  k_reduce<<<64, 256, 0, stream>>>(apPart, cnPart, acc4, outCnt, acc4);
  k_final<<<1, 64, 0, stream>>>(acc4, out3);
}